// Round 12
// baseline (731.031 us; speedup 1.0000x reference)
//
#include <hip/hip_runtime.h>
#include <hip/hip_bf16.h>
#include <hip/hip_fp16.h>

// db4 analysis filters (DEC_LO, DEC_HI[k] = (-1)^(k+1) DEC_LO[7-k])
#define DL_INIT {-0.010597401784997278f, 0.032883011666982945f, 0.030841381835986965f, \
  -0.18703481171888114f, -0.02798376941698385f, 0.6308807679295904f, \
  0.7148465705525415f, 0.23037781330885523f}
#define DH_INIT {-0.23037781330885523f, 0.7148465705525415f, -0.6308807679295904f, \
  -0.02798376941698385f, 0.18703481171888114f, 0.030841381835986965f, \
  -0.032883011666982945f, -0.010597401784997278f}

#define SP 1232
#define PLANE 2523136

typedef _Float16 half_t;
typedef _Float16 half8 __attribute__((ext_vector_type(8)));
typedef _Float16 half2v __attribute__((ext_vector_type(2)));
using f32x4 = __attribute__((ext_vector_type(4))) float;

// ---------------- fc0: fp32 in -> fp16 h ----------------
__global__ __launch_bounds__(256) void k_fc0(const float* __restrict__ x,
    const float* __restrict__ w, const float* __restrict__ bias,
    half_t* __restrict__ h)
{
    int g = blockIdx.x * 256 + threadIdx.x;
    int b = g >> 18, c = (g >> 12) & 63, sx = (g >> 6) & 63, sy = g & 63;
    const float* xp = x + ((b * 64 + sx) * 64 + sy) * 3;
    float f3 = (float)sx / 63.0f, f4 = (float)sy / 63.0f;
    float acc = bias[c];
    acc = fmaf(xp[0], w[0 * 64 + c], acc);
    acc = fmaf(xp[1], w[1 * 64 + c], acc);
    acc = fmaf(xp[2], w[2 * 64 + c], acc);
    acc = fmaf(f3,    w[3 * 64 + c], acc);
    acc = fmaf(f4,    w[4 * 64 + c], acc);
    h[g] = (half_t)acc;
}

// ---------------- DWT2 (both axes fused per (b,c)), fp16 I/O ----------------
__global__ __launch_bounds__(256) void k_dwt(const half_t* __restrict__ h,
    half_t* __restrict__ s)
{
    constexpr float DL[8] = DL_INIT;
    constexpr float DH[8] = DH_INIT;
    __shared__ float xs[4096];
    __shared__ float tlo[2240];
    __shared__ float thi[2240];
    int bc = blockIdx.x, t = threadIdx.x;
    const half_t* hp = h + bc * 4096;
    #pragma unroll
    for (int k = 0; k < 16; ++k) xs[t + k * 256] = (float)hp[t + k * 256];
    __syncthreads();
    for (int u = t; u < 2240; u += 256) {
        int sx = u / 35, oy = u - sx * 35;
        int y0 = 2 * oy + 1;
        float al = 0.f, ah = 0.f;
        #pragma unroll
        for (int j = 0; j < 8; ++j) {
            int yy = y0 - j;
            yy = (yy < 0) ? (-1 - yy) : yy;
            yy = (yy > 63) ? (127 - yy) : yy;
            float v = xs[sx * 64 + yy];
            al = fmaf(DL[j], v, al);
            ah = fmaf(DH[j], v, ah);
        }
        tlo[u] = al; thi[u] = ah;
    }
    __syncthreads();
    half_t* s0 = s + bc * SP;
    for (int u = t; u < 1225; u += 256) {
        int ox = u / 35, oy = u - ox * 35;
        int x0 = 2 * ox + 1;
        float a_ll = 0.f, a_lh = 0.f, a_hl = 0.f, a_hh = 0.f;
        #pragma unroll
        for (int j = 0; j < 8; ++j) {
            int xx = x0 - j;
            xx = (xx < 0) ? (-1 - xx) : xx;
            xx = (xx > 63) ? (127 - xx) : xx;
            float vl = tlo[xx * 35 + oy];
            float vh = thi[xx * 35 + oy];
            a_ll = fmaf(DL[j], vl, a_ll);
            a_lh = fmaf(DH[j], vl, a_lh);
            a_hl = fmaf(DL[j], vh, a_hl);
            a_hh = fmaf(DH[j], vh, a_hh);
        }
        s0[u]             = (half_t)a_ll;
        s0[PLANE + u]     = (half_t)a_lh;
        s0[2 * PLANE + u] = (half_t)a_hl;
        s0[3 * PLANE + u] = (half_t)a_hh;
    }
}

// ---------------- mul2d: 4-way o-split for occupancy (1 o x 32 b per thread) --------
// Block 128 thr = 8 px x 16 o. grid.x = 616 (154 tiles x 4 og), grid.y = z.
// w-path: plain in-loop loads (R11's prefetch/nontemporal reverted); latency hidden
// by 2x occupancy (2464 blocks -> ~4.8 waves/SIMD).
__global__ __launch_bounds__(128) void k_mul2d(const half_t* __restrict__ sIn,
    const float* __restrict__ W, half_t* __restrict__ mOut)
{
    // bijective XCD swizzle over 616 = 8 * 77
    int raw = blockIdx.x;
    int xcd = raw & 7, kk = raw >> 3;
    int sid = xcd * 77 + kk;
    int tile = sid >> 2, og = sid & 3;
    int z = blockIdx.y;
    int p0 = tile * 8;
    const half_t* in = sIn + (size_t)z * PLANE;
    const float* w   = W   + (size_t)z * 5017600;
    half_t* out = mOut + (size_t)z * PLANE;
    int t = threadIdx.x;
    int p = t & 7, wg = t >> 3;
    int oA = og * 16 + wg;               // one o per thread
    int pp = min(p0 + p, 1224);
    float a[32];
    #pragma unroll
    for (int b = 0; b < 32; ++b) a[b] = 0.f;
    __shared__ float inp[4 * 8 * 34];    // [ii][pl][b pad 34]

    const half_t* src[8];
    int dst[8];
    #pragma unroll
    for (int k = 0; k < 8; ++k) {
        int e = t + k * 128;             // e = (b*4+ii)*8 + pl
        int pl = e & 7, ii = (e >> 3) & 3, b = e >> 5;
        int gp = min(p0 + pl, 1224);
        src[k] = in + (b * 64 + ii) * SP + gp;
        dst[k] = (ii * 8 + pl) * 34 + b;
    }
    float r[8];
    #pragma unroll
    for (int k = 0; k < 8; ++k) r[k] = (float)src[k][0];

    for (int ic = 0; ic < 64; ic += 4) {
        __syncthreads();
        #pragma unroll
        for (int k = 0; k < 8; ++k) inp[dst[k]] = r[k];
        __syncthreads();
        if (ic < 60) {
            #pragma unroll
            for (int k = 0; k < 8; ++k) r[k] = (float)src[k][(ic + 4) * SP];
        }
        #pragma unroll
        for (int ii = 0; ii < 4; ++ii) {
            int i = ic + ii;
            float w0 = w[(i * 64 + oA) * 1225 + pp];
            const float2* ip = reinterpret_cast<const float2*>(&inp[(ii * 8 + p) * 34]);
            #pragma unroll
            for (int bq = 0; bq < 16; ++bq) {
                float2 v = ip[bq];
                a[bq * 2]     = fmaf(v.x, w0, a[bq * 2]);
                a[bq * 2 + 1] = fmaf(v.y, w0, a[bq * 2 + 1]);
            }
        }
    }
    if (p0 + p < 1225) {
        #pragma unroll
        for (int b = 0; b < 32; ++b)
            out[(b * 64 + oA) * SP + p0 + p] = (half_t)a[b];
    }
}

// ---------------- column synthesis, fp16 I/O ----------------
__global__ __launch_bounds__(256) void k_idwt_col(const half_t* __restrict__ m,
    half_t* __restrict__ uLo, half_t* __restrict__ uHi)
{
    constexpr float DL[8] = DL_INIT;
    constexpr float DH[8] = DH_INIT;
    int bc = blockIdx.x, z = blockIdx.y, t = threadIdx.x;
    const half_t* lo = m + (size_t)(z * 2) * PLANE + bc * SP;
    const half_t* hi = m + (size_t)(z * 2 + 1) * PLANE + bc * SP;
    half_t* uo = (z ? uHi : uLo) + bc * 2240;
    for (int u = t; u < 2240; u += 256) {
        int n = u / 35, oy = u - n * 35;
        int q = n & 1, mm = n >> 1;
        float cl0 = q ? DL[0] : DL[1], cl1 = q ? DL[2] : DL[3];
        float cl2 = q ? DL[4] : DL[5], cl3 = q ? DL[6] : DL[7];
        float ch0 = q ? DH[0] : DH[1], ch1 = q ? DH[2] : DH[3];
        float ch2 = q ? DH[4] : DH[5], ch3 = q ? DH[6] : DH[7];
        int base = mm * 35 + oy;
        float a = cl0 * (float)lo[base];
        a = fmaf(cl1, (float)lo[base + 35], a);
        a = fmaf(cl2, (float)lo[base + 70], a);
        a = fmaf(cl3, (float)lo[base + 105], a);
        a = fmaf(ch0, (float)hi[base], a);
        a = fmaf(ch1, (float)hi[base + 35], a);
        a = fmaf(ch2, (float)hi[base + 70], a);
        a = fmaf(ch3, (float)hi[base + 105], a);
        uo[u] = (half_t)a;
    }
}

// ---------------- pconv + row synthesis + bias + relu, fp16 I/O ----------------
__global__ __launch_bounds__(256) void k_pconv_idwt(const half_t* __restrict__ h,
    const half_t* __restrict__ uLo, const half_t* __restrict__ uHi,
    const float* __restrict__ cw, const float* __restrict__ cb,
    half_t* __restrict__ hOut)
{
    constexpr float DL[8] = DL_INIT;
    constexpr float DH[8] = DH_INIT;
    __shared__ float cwt[4096];          // [i][o] fp32, 16 KB
    __shared__ half_t hs[64][128];       // [c][px] fp16, 16 KB
    int t = threadIdx.x;
    #pragma unroll
    for (int k = 0; k < 16; ++k) {
        int e = t + k * 256;
        cwt[e] = cw[(e & 63) * 64 + (e >> 6)];
    }
    int px0g = blockIdx.x * 128;
    int b = px0g >> 12, pxl0 = px0g & 4095;
    const half_t* hb = h + ((size_t)b << 18) + pxl0;
    #pragma unroll
    for (int k = 0; k < 4; ++k) {
        int e = t + k * 256;
        int c = e >> 4, col = (e & 15) * 8;
        *reinterpret_cast<half8*>(&hs[c][col]) =
            *reinterpret_cast<const half8*>(&hb[(c << 12) + col]);
    }
    __syncthreads();
    int p2 = t & 63, og = t >> 6;
    int o0 = og * 16;
    float acc0[16], acc1[16];
    #pragma unroll
    for (int oo = 0; oo < 16; ++oo) { acc0[oo] = cb[o0 + oo]; acc1[oo] = acc0[oo]; }
    for (int i = 0; i < 64; ++i) {
        half2v hraw = *reinterpret_cast<const half2v*>(&hs[i][p2 * 2]);
        float hvx = (float)hraw[0], hvy = (float)hraw[1];
        const float4* wv = reinterpret_cast<const float4*>(&cwt[i * 64 + o0]);
        #pragma unroll
        for (int q4 = 0; q4 < 4; ++q4) {
            float4 wq = wv[q4];
            acc0[q4 * 4 + 0] = fmaf(hvx, wq.x, acc0[q4 * 4 + 0]);
            acc1[q4 * 4 + 0] = fmaf(hvy, wq.x, acc1[q4 * 4 + 0]);
            acc0[q4 * 4 + 1] = fmaf(hvx, wq.y, acc0[q4 * 4 + 1]);
            acc1[q4 * 4 + 1] = fmaf(hvy, wq.y, acc1[q4 * 4 + 1]);
            acc0[q4 * 4 + 2] = fmaf(hvx, wq.z, acc0[q4 * 4 + 2]);
            acc1[q4 * 4 + 2] = fmaf(hvy, wq.z, acc1[q4 * 4 + 2]);
            acc0[q4 * 4 + 3] = fmaf(hvx, wq.w, acc0[q4 * 4 + 3]);
            acc1[q4 * 4 + 3] = fmaf(hvy, wq.w, acc1[q4 * 4 + 3]);
        }
    }
    int pxe = pxl0 + 2 * p2;
    int sx = pxe >> 6, sy = pxe & 63;
    int mm = sy >> 1;
    const half_t* lp = uLo + (((size_t)(b << 6) + o0) * 2240) + sx * 35 + mm;
    const half_t* hq = uHi + (((size_t)(b << 6) + o0) * 2240) + sx * 35 + mm;
    half_t* op = hOut + ((size_t)b << 18) + pxe;
    #pragma unroll
    for (int oo = 0; oo < 16; ++oo) {
        const half_t* l = lp + oo * 2240;
        const half_t* g = hq + oo * 2240;
        float l0 = (float)l[0], l1 = (float)l[1], l2 = (float)l[2], l3 = (float)l[3];
        float g0 = (float)g[0], g1 = (float)g[1], g2 = (float)g[2], g3 = (float)g[3];
        float xe = DL[1] * l0;
        xe = fmaf(DL[3], l1, xe); xe = fmaf(DL[5], l2, xe); xe = fmaf(DL[7], l3, xe);
        xe = fmaf(DH[1], g0, xe); xe = fmaf(DH[3], g1, xe);
        xe = fmaf(DH[5], g2, xe); xe = fmaf(DH[7], g3, xe);
        float xo = DL[0] * l0;
        xo = fmaf(DL[2], l1, xo); xo = fmaf(DL[4], l2, xo); xo = fmaf(DL[6], l3, xo);
        xo = fmaf(DH[0], g0, xo); xo = fmaf(DH[2], g1, xo);
        xo = fmaf(DH[4], g2, xo); xo = fmaf(DH[6], g3, xo);
        half2v rv;
        rv[0] = (half_t)fmaxf(acc0[oo] + xe, 0.f);
        rv[1] = (half_t)fmaxf(acc1[oo] + xo, 0.f);
        *reinterpret_cast<half2v*>(&op[(size_t)(o0 + oo) << 12]) = rv;
    }
}

// ---------------- fc1+relu+fc2 via f16 MFMA (h is fp16 already) ----------------
__global__ __launch_bounds__(256) void k_fc_final(const half_t* __restrict__ h,
    const float* __restrict__ w1, const float* __restrict__ b1,
    const float* __restrict__ w2, const float* __restrict__ b2,
    float* __restrict__ out)
{
    int t = threadIdx.x;
    int l = t & 63, wid = t >> 6;
    int lr = l & 15, lg = l >> 4;
    float part[2][4];
    #pragma unroll
    for (int it = 0; it < 2; ++it)
        #pragma unroll
        for (int r = 0; r < 4; ++r) part[it][r] = 0.f;

    int pxbase = blockIdx.x * 128 + wid * 32;

    for (int nh = 0; nh < 2; ++nh) {
        half8 Bf[8][2];
        #pragma unroll
        for (int tt = 0; tt < 8; ++tt) {
            #pragma unroll
            for (int kh = 0; kh < 2; ++kh) {
                const float* wp = w1 + (kh * 32 + lg * 8) * 256 + nh * 128 + tt * 16 + lr;
                half8 f;
                #pragma unroll
                for (int e = 0; e < 8; ++e) f[e] = (half_t)wp[e * 256];
                Bf[tt][kh] = f;
            }
        }
        #pragma unroll
        for (int it = 0; it < 2; ++it) {
            int pxg = pxbase + it * 16;
            int b = pxg >> 12, pxl = pxg & 4095;
            const half_t* hp = h + ((size_t)b << 18) + pxl + lr + (size_t)(lg * 8) * 4096;
            half8 Af[2];
            #pragma unroll
            for (int kh = 0; kh < 2; ++kh) {
                half8 f;
                #pragma unroll
                for (int e = 0; e < 8; ++e)
                    f[e] = hp[(size_t)(kh * 32 + e) * 4096];
                Af[kh] = f;
            }
            #pragma unroll
            for (int tt = 0; tt < 8; ++tt) {
                f32x4 acc = {0.f, 0.f, 0.f, 0.f};
                acc = __builtin_amdgcn_mfma_f32_16x16x32_f16(Af[0], Bf[tt][0], acc, 0, 0, 0);
                acc = __builtin_amdgcn_mfma_f32_16x16x32_f16(Af[1], Bf[tt][1], acc, 0, 0, 0);
                int n = nh * 128 + tt * 16 + lr;
                float bj = b1[n], wj = w2[n];
                #pragma unroll
                for (int r = 0; r < 4; ++r)
                    part[it][r] = fmaf(fmaxf(acc[r] + bj, 0.f), wj, part[it][r]);
            }
        }
    }
    float bb = b2[0];
    #pragma unroll
    for (int it = 0; it < 2; ++it) {
        #pragma unroll
        for (int r = 0; r < 4; ++r) {
            float v = part[it][r];
            v += __shfl_xor(v, 1);
            v += __shfl_xor(v, 2);
            v += __shfl_xor(v, 4);
            v += __shfl_xor(v, 8);
            if (lr == 0) out[pxbase + it * 16 + lg * 4 + r] = v + bb;
        }
    }
}

extern "C" void kernel_launch(void* const* d_in, const int* in_sizes, int n_in,
                              void* d_out, int out_size, void* d_ws, size_t ws_size,
                              hipStream_t stream)
{
    const float* x     = (const float*)d_in[0];
    const float* fc0w  = (const float*)d_in[1];
    const float* fc0b  = (const float*)d_in[2];
    const float* wno   = (const float*)d_in[3];
    const float* convw = (const float*)d_in[4];
    const float* convb = (const float*)d_in[5];
    const float* fc1w  = (const float*)d_in[6];
    const float* fc1b  = (const float*)d_in[7];
    const float* fc2w  = (const float*)d_in[8];
    const float* fc2b  = (const float*)d_in[9];
    (void)in_sizes; (void)n_in; (void)out_size; (void)ws_size;

    half_t* ws  = (half_t*)d_ws;
    half_t* hA  = ws;
    half_t* hB  = hA + 8388608;
    half_t* sU  = hB + 8388608;
    half_t* mB  = sU + 4 * (size_t)PLANE;
    half_t* uLo = sU;
    half_t* uHi = sU + 4587520;

    k_fc0<<<32768, 256, 0, stream>>>(x, fc0w, fc0b, hA);

    half_t* hin = hA;
    half_t* hout = hB;
    for (int blk = 0; blk < 4; ++blk) {
        k_dwt<<<2048, 256, 0, stream>>>(hin, sU);
        k_mul2d<<<dim3(616, 4), 128, 0, stream>>>(sU, wno + (size_t)blk * 20070400, mB);
        k_idwt_col<<<dim3(2048, 2), 256, 0, stream>>>(mB, uLo, uHi);
        k_pconv_idwt<<<1024, 256, 0, stream>>>(hin, uLo, uHi,
                                               convw + blk * 4096, convb + blk * 64, hout);
        half_t* tmp = hin; hin = hout; hout = tmp;
    }

    k_fc_final<<<1024, 256, 0, stream>>>(hin, fc1w, fc1b, fc2w, fc2b,
                                         (float*)d_out);
}

// Round 13
// 488.790 us; speedup vs baseline: 1.4956x; 1.4956x over previous
//
#include <hip/hip_runtime.h>
#include <hip/hip_bf16.h>
#include <hip/hip_fp16.h>

// db4 analysis filters (DEC_LO, DEC_HI[k] = (-1)^(k+1) DEC_LO[7-k])
#define DL_INIT {-0.010597401784997278f, 0.032883011666982945f, 0.030841381835986965f, \
  -0.18703481171888114f, -0.02798376941698385f, 0.6308807679295904f, \
  0.7148465705525415f, 0.23037781330885523f}
#define DH_INIT {-0.23037781330885523f, 0.7148465705525415f, -0.6308807679295904f, \
  -0.02798376941698385f, 0.18703481171888114f, 0.030841381835986965f, \
  -0.032883011666982945f, -0.010597401784997278f}

#define SP 1232
#define PLANE 2523136

typedef _Float16 half_t;
typedef _Float16 half8 __attribute__((ext_vector_type(8)));
typedef _Float16 half2v __attribute__((ext_vector_type(2)));
using f32x4 = __attribute__((ext_vector_type(4))) float;

// ---------------- fc0: fp32 in -> fp16 h ----------------
__global__ __launch_bounds__(256) void k_fc0(const float* __restrict__ x,
    const float* __restrict__ w, const float* __restrict__ bias,
    half_t* __restrict__ h)
{
    int g = blockIdx.x * 256 + threadIdx.x;
    int b = g >> 18, c = (g >> 12) & 63, sx = (g >> 6) & 63, sy = g & 63;
    const float* xp = x + ((b * 64 + sx) * 64 + sy) * 3;
    float f3 = (float)sx / 63.0f, f4 = (float)sy / 63.0f;
    float acc = bias[c];
    acc = fmaf(xp[0], w[0 * 64 + c], acc);
    acc = fmaf(xp[1], w[1 * 64 + c], acc);
    acc = fmaf(xp[2], w[2 * 64 + c], acc);
    acc = fmaf(f3,    w[3 * 64 + c], acc);
    acc = fmaf(f4,    w[4 * 64 + c], acc);
    h[g] = (half_t)acc;
}

// ---------------- DWT2 (both axes fused per (b,c)), fp16 I/O ----------------
__global__ __launch_bounds__(256) void k_dwt(const half_t* __restrict__ h,
    half_t* __restrict__ s)
{
    constexpr float DL[8] = DL_INIT;
    constexpr float DH[8] = DH_INIT;
    __shared__ float xs[4096];
    __shared__ float tlo[2240];
    __shared__ float thi[2240];
    int bc = blockIdx.x, t = threadIdx.x;
    const half_t* hp = h + bc * 4096;
    #pragma unroll
    for (int k = 0; k < 16; ++k) xs[t + k * 256] = (float)hp[t + k * 256];
    __syncthreads();
    for (int u = t; u < 2240; u += 256) {
        int sx = u / 35, oy = u - sx * 35;
        int y0 = 2 * oy + 1;
        float al = 0.f, ah = 0.f;
        #pragma unroll
        for (int j = 0; j < 8; ++j) {
            int yy = y0 - j;
            yy = (yy < 0) ? (-1 - yy) : yy;
            yy = (yy > 63) ? (127 - yy) : yy;
            float v = xs[sx * 64 + yy];
            al = fmaf(DL[j], v, al);
            ah = fmaf(DH[j], v, ah);
        }
        tlo[u] = al; thi[u] = ah;
    }
    __syncthreads();
    half_t* s0 = s + bc * SP;
    for (int u = t; u < 1225; u += 256) {
        int ox = u / 35, oy = u - ox * 35;
        int x0 = 2 * ox + 1;
        float a_ll = 0.f, a_lh = 0.f, a_hl = 0.f, a_hh = 0.f;
        #pragma unroll
        for (int j = 0; j < 8; ++j) {
            int xx = x0 - j;
            xx = (xx < 0) ? (-1 - xx) : xx;
            xx = (xx > 63) ? (127 - xx) : xx;
            float vl = tlo[xx * 35 + oy];
            float vh = thi[xx * 35 + oy];
            a_ll = fmaf(DL[j], vl, a_ll);
            a_lh = fmaf(DH[j], vl, a_lh);
            a_hl = fmaf(DL[j], vh, a_hl);
            a_hh = fmaf(DH[j], vh, a_hh);
        }
        s0[u]             = (half_t)a_ll;
        s0[PLANE + u]     = (half_t)a_lh;
        s0[2 * PLANE + u] = (half_t)a_hl;
        s0[3 * PLANE + u] = (half_t)a_hh;
    }
}

// ---------------- mul2d: fp16 in/out, fp32 weights, reg-dbuf prefetch (R10 optimum) --
// 8 px x 32 o (og half) x 32 b; thread = (p in 8, wg in 16) -> 2 o x 32 b.
// Local optimum: each float2 LDS read feeds 4 FMAs. Both the w-prefetch variant (R11)
// and the 4-way o-split (R12) regressed -25%/-50% vs this shape.
__global__ __launch_bounds__(128) void k_mul2d(const half_t* __restrict__ sIn,
    const float* __restrict__ W, half_t* __restrict__ mOut)
{
    int raw = blockIdx.x;
    int xcd = raw & 7, kk = raw >> 3;
    int sid = (xcd < 4) ? (xcd * 39 + kk) : (156 + (xcd - 4) * 38 + kk);
    int tile = sid >> 1, og = sid & 1;
    int z = blockIdx.y;
    int p0 = tile * 8;
    const half_t* in = sIn + (size_t)z * PLANE;
    const float* w   = W   + (size_t)z * 5017600;
    half_t* out = mOut + (size_t)z * PLANE;
    int t = threadIdx.x;
    int p = t & 7, wg = t >> 3;
    int oA = og * 32 + wg * 2;
    int pp = min(p0 + p, 1224);
    float a0[32], a1[32];
    #pragma unroll
    for (int b = 0; b < 32; ++b) { a0[b] = 0.f; a1[b] = 0.f; }
    __shared__ float inp[4 * 8 * 34];

    const half_t* src[8];
    int dst[8];
    #pragma unroll
    for (int k = 0; k < 8; ++k) {
        int e = t + k * 128;
        int pl = e & 7, ii = (e >> 3) & 3, b = e >> 5;
        int gp = min(p0 + pl, 1224);
        src[k] = in + (b * 64 + ii) * SP + gp;
        dst[k] = (ii * 8 + pl) * 34 + b;
    }
    float r[8];
    #pragma unroll
    for (int k = 0; k < 8; ++k) r[k] = (float)src[k][0];

    for (int ic = 0; ic < 64; ic += 4) {
        __syncthreads();
        #pragma unroll
        for (int k = 0; k < 8; ++k) inp[dst[k]] = r[k];
        __syncthreads();
        if (ic < 60) {
            #pragma unroll
            for (int k = 0; k < 8; ++k) r[k] = (float)src[k][(ic + 4) * SP];
        }
        #pragma unroll
        for (int ii = 0; ii < 4; ++ii) {
            int i = ic + ii;
            float w0 = w[(i * 64 + oA) * 1225 + pp];
            float w1 = w[(i * 64 + oA + 1) * 1225 + pp];
            const float2* ip = reinterpret_cast<const float2*>(&inp[(ii * 8 + p) * 34]);
            #pragma unroll
            for (int bq = 0; bq < 16; ++bq) {
                float2 v = ip[bq];
                a0[bq * 2]     = fmaf(v.x, w0, a0[bq * 2]);
                a1[bq * 2]     = fmaf(v.x, w1, a1[bq * 2]);
                a0[bq * 2 + 1] = fmaf(v.y, w0, a0[bq * 2 + 1]);
                a1[bq * 2 + 1] = fmaf(v.y, w1, a1[bq * 2 + 1]);
            }
        }
    }
    if (p0 + p < 1225) {
        #pragma unroll
        for (int b = 0; b < 32; ++b) {
            out[(b * 64 + oA) * SP + p0 + p]     = (half_t)a0[b];
            out[(b * 64 + oA + 1) * SP + p0 + p] = (half_t)a1[b];
        }
    }
}

// ---------------- column synthesis, fp16 I/O ----------------
__global__ __launch_bounds__(256) void k_idwt_col(const half_t* __restrict__ m,
    half_t* __restrict__ uLo, half_t* __restrict__ uHi)
{
    constexpr float DL[8] = DL_INIT;
    constexpr float DH[8] = DH_INIT;
    int bc = blockIdx.x, z = blockIdx.y, t = threadIdx.x;
    const half_t* lo = m + (size_t)(z * 2) * PLANE + bc * SP;
    const half_t* hi = m + (size_t)(z * 2 + 1) * PLANE + bc * SP;
    half_t* uo = (z ? uHi : uLo) + bc * 2240;
    for (int u = t; u < 2240; u += 256) {
        int n = u / 35, oy = u - n * 35;
        int q = n & 1, mm = n >> 1;
        float cl0 = q ? DL[0] : DL[1], cl1 = q ? DL[2] : DL[3];
        float cl2 = q ? DL[4] : DL[5], cl3 = q ? DL[6] : DL[7];
        float ch0 = q ? DH[0] : DH[1], ch1 = q ? DH[2] : DH[3];
        float ch2 = q ? DH[4] : DH[5], ch3 = q ? DH[6] : DH[7];
        int base = mm * 35 + oy;
        float a = cl0 * (float)lo[base];
        a = fmaf(cl1, (float)lo[base + 35], a);
        a = fmaf(cl2, (float)lo[base + 70], a);
        a = fmaf(cl3, (float)lo[base + 105], a);
        a = fmaf(ch0, (float)hi[base], a);
        a = fmaf(ch1, (float)hi[base + 35], a);
        a = fmaf(ch2, (float)hi[base + 70], a);
        a = fmaf(ch3, (float)hi[base + 105], a);
        uo[u] = (half_t)a;
    }
}

// ---------------- pconv + row synthesis + bias + relu, fp16 I/O ----------------
__global__ __launch_bounds__(256) void k_pconv_idwt(const half_t* __restrict__ h,
    const half_t* __restrict__ uLo, const half_t* __restrict__ uHi,
    const float* __restrict__ cw, const float* __restrict__ cb,
    half_t* __restrict__ hOut)
{
    constexpr float DL[8] = DL_INIT;
    constexpr float DH[8] = DH_INIT;
    __shared__ float cwt[4096];          // [i][o] fp32, 16 KB
    __shared__ half_t hs[64][128];       // [c][px] fp16, 16 KB
    int t = threadIdx.x;
    #pragma unroll
    for (int k = 0; k < 16; ++k) {
        int e = t + k * 256;
        cwt[e] = cw[(e & 63) * 64 + (e >> 6)];
    }
    int px0g = blockIdx.x * 128;
    int b = px0g >> 12, pxl0 = px0g & 4095;
    const half_t* hb = h + ((size_t)b << 18) + pxl0;
    #pragma unroll
    for (int k = 0; k < 4; ++k) {
        int e = t + k * 256;
        int c = e >> 4, col = (e & 15) * 8;
        *reinterpret_cast<half8*>(&hs[c][col]) =
            *reinterpret_cast<const half8*>(&hb[(c << 12) + col]);
    }
    __syncthreads();
    int p2 = t & 63, og = t >> 6;
    int o0 = og * 16;
    float acc0[16], acc1[16];
    #pragma unroll
    for (int oo = 0; oo < 16; ++oo) { acc0[oo] = cb[o0 + oo]; acc1[oo] = acc0[oo]; }
    for (int i = 0; i < 64; ++i) {
        half2v hraw = *reinterpret_cast<const half2v*>(&hs[i][p2 * 2]);
        float hvx = (float)hraw[0], hvy = (float)hraw[1];
        const float4* wv = reinterpret_cast<const float4*>(&cwt[i * 64 + o0]);
        #pragma unroll
        for (int q4 = 0; q4 < 4; ++q4) {
            float4 wq = wv[q4];
            acc0[q4 * 4 + 0] = fmaf(hvx, wq.x, acc0[q4 * 4 + 0]);
            acc1[q4 * 4 + 0] = fmaf(hvy, wq.x, acc1[q4 * 4 + 0]);
            acc0[q4 * 4 + 1] = fmaf(hvx, wq.y, acc0[q4 * 4 + 1]);
            acc1[q4 * 4 + 1] = fmaf(hvy, wq.y, acc1[q4 * 4 + 1]);
            acc0[q4 * 4 + 2] = fmaf(hvx, wq.z, acc0[q4 * 4 + 2]);
            acc1[q4 * 4 + 2] = fmaf(hvy, wq.z, acc1[q4 * 4 + 2]);
            acc0[q4 * 4 + 3] = fmaf(hvx, wq.w, acc0[q4 * 4 + 3]);
            acc1[q4 * 4 + 3] = fmaf(hvy, wq.w, acc1[q4 * 4 + 3]);
        }
    }
    int pxe = pxl0 + 2 * p2;
    int sx = pxe >> 6, sy = pxe & 63;
    int mm = sy >> 1;
    const half_t* lp = uLo + (((size_t)(b << 6) + o0) * 2240) + sx * 35 + mm;
    const half_t* hq = uHi + (((size_t)(b << 6) + o0) * 2240) + sx * 35 + mm;
    half_t* op = hOut + ((size_t)b << 18) + pxe;
    #pragma unroll
    for (int oo = 0; oo < 16; ++oo) {
        const half_t* l = lp + oo * 2240;
        const half_t* g = hq + oo * 2240;
        float l0 = (float)l[0], l1 = (float)l[1], l2 = (float)l[2], l3 = (float)l[3];
        float g0 = (float)g[0], g1 = (float)g[1], g2 = (float)g[2], g3 = (float)g[3];
        float xe = DL[1] * l0;
        xe = fmaf(DL[3], l1, xe); xe = fmaf(DL[5], l2, xe); xe = fmaf(DL[7], l3, xe);
        xe = fmaf(DH[1], g0, xe); xe = fmaf(DH[3], g1, xe);
        xe = fmaf(DH[5], g2, xe); xe = fmaf(DH[7], g3, xe);
        float xo = DL[0] * l0;
        xo = fmaf(DL[2], l1, xo); xo = fmaf(DL[4], l2, xo); xo = fmaf(DL[6], l3, xo);
        xo = fmaf(DH[0], g0, xo); xo = fmaf(DH[2], g1, xo);
        xo = fmaf(DH[4], g2, xo); xo = fmaf(DH[6], g3, xo);
        half2v rv;
        rv[0] = (half_t)fmaxf(acc0[oo] + xe, 0.f);
        rv[1] = (half_t)fmaxf(acc1[oo] + xo, 0.f);
        *reinterpret_cast<half2v*>(&op[(size_t)(o0 + oo) << 12]) = rv;
    }
}

// ---------------- fc1+relu+fc2 via f16 MFMA (h is fp16 already) ----------------
__global__ __launch_bounds__(256) void k_fc_final(const half_t* __restrict__ h,
    const float* __restrict__ w1, const float* __restrict__ b1,
    const float* __restrict__ w2, const float* __restrict__ b2,
    float* __restrict__ out)
{
    int t = threadIdx.x;
    int l = t & 63, wid = t >> 6;
    int lr = l & 15, lg = l >> 4;
    float part[2][4];
    #pragma unroll
    for (int it = 0; it < 2; ++it)
        #pragma unroll
        for (int r = 0; r < 4; ++r) part[it][r] = 0.f;

    int pxbase = blockIdx.x * 128 + wid * 32;

    for (int nh = 0; nh < 2; ++nh) {
        half8 Bf[8][2];
        #pragma unroll
        for (int tt = 0; tt < 8; ++tt) {
            #pragma unroll
            for (int kh = 0; kh < 2; ++kh) {
                const float* wp = w1 + (kh * 32 + lg * 8) * 256 + nh * 128 + tt * 16 + lr;
                half8 f;
                #pragma unroll
                for (int e = 0; e < 8; ++e) f[e] = (half_t)wp[e * 256];
                Bf[tt][kh] = f;
            }
        }
        #pragma unroll
        for (int it = 0; it < 2; ++it) {
            int pxg = pxbase + it * 16;
            int b = pxg >> 12, pxl = pxg & 4095;
            const half_t* hp = h + ((size_t)b << 18) + pxl + lr + (size_t)(lg * 8) * 4096;
            half8 Af[2];
            #pragma unroll
            for (int kh = 0; kh < 2; ++kh) {
                half8 f;
                #pragma unroll
                for (int e = 0; e < 8; ++e)
                    f[e] = hp[(size_t)(kh * 32 + e) * 4096];
                Af[kh] = f;
            }
            #pragma unroll
            for (int tt = 0; tt < 8; ++tt) {
                f32x4 acc = {0.f, 0.f, 0.f, 0.f};
                acc = __builtin_amdgcn_mfma_f32_16x16x32_f16(Af[0], Bf[tt][0], acc, 0, 0, 0);
                acc = __builtin_amdgcn_mfma_f32_16x16x32_f16(Af[1], Bf[tt][1], acc, 0, 0, 0);
                int n = nh * 128 + tt * 16 + lr;
                float bj = b1[n], wj = w2[n];
                #pragma unroll
                for (int r = 0; r < 4; ++r)
                    part[it][r] = fmaf(fmaxf(acc[r] + bj, 0.f), wj, part[it][r]);
            }
        }
    }
    float bb = b2[0];
    #pragma unroll
    for (int it = 0; it < 2; ++it) {
        #pragma unroll
        for (int r = 0; r < 4; ++r) {
            float v = part[it][r];
            v += __shfl_xor(v, 1);
            v += __shfl_xor(v, 2);
            v += __shfl_xor(v, 4);
            v += __shfl_xor(v, 8);
            if (lr == 0) out[pxbase + it * 16 + lg * 4 + r] = v + bb;
        }
    }
}

extern "C" void kernel_launch(void* const* d_in, const int* in_sizes, int n_in,
                              void* d_out, int out_size, void* d_ws, size_t ws_size,
                              hipStream_t stream)
{
    const float* x     = (const float*)d_in[0];
    const float* fc0w  = (const float*)d_in[1];
    const float* fc0b  = (const float*)d_in[2];
    const float* wno   = (const float*)d_in[3];
    const float* convw = (const float*)d_in[4];
    const float* convb = (const float*)d_in[5];
    const float* fc1w  = (const float*)d_in[6];
    const float* fc1b  = (const float*)d_in[7];
    const float* fc2w  = (const float*)d_in[8];
    const float* fc2b  = (const float*)d_in[9];
    (void)in_sizes; (void)n_in; (void)out_size; (void)ws_size;

    half_t* ws  = (half_t*)d_ws;
    half_t* hA  = ws;
    half_t* hB  = hA + 8388608;
    half_t* sU  = hB + 8388608;
    half_t* mB  = sU + 4 * (size_t)PLANE;
    half_t* uLo = sU;
    half_t* uHi = sU + 4587520;

    k_fc0<<<32768, 256, 0, stream>>>(x, fc0w, fc0b, hA);

    half_t* hin = hA;
    half_t* hout = hB;
    for (int blk = 0; blk < 4; ++blk) {
        k_dwt<<<2048, 256, 0, stream>>>(hin, sU);
        k_mul2d<<<dim3(308, 4), 128, 0, stream>>>(sU, wno + (size_t)blk * 20070400, mB);
        k_idwt_col<<<dim3(2048, 2), 256, 0, stream>>>(mB, uLo, uHi);
        k_pconv_idwt<<<1024, 256, 0, stream>>>(hin, uLo, uHi,
                                               convw + blk * 4096, convb + blk * 64, hout);
        half_t* tmp = hin; hin = hout; hout = tmp;
    }

    k_fc_final<<<1024, 256, 0, stream>>>(hin, fc1w, fc1b, fc2w, fc2b,
                                         (float*)d_out);
}